// Round 9
// baseline (288.151 us; speedup 1.0000x reference)
//
#include <hip/hip_runtime.h>

#define BB    8
#define LQN   2048
#define LKVN  2048
#define DQ    128
#define DVN   128
#define QT    32            // Q rows per block (2 groups of 16)
#define KTI   128           // KV per staged tile (4 slices x 32)
#define NT    (LKVN / KTI)  // 16 tiles
#define OSTR  132           // osum row stride (f32)

typedef short short8 __attribute__((ext_vector_type(8)));
typedef short short4v __attribute__((ext_vector_type(4)));
typedef float f32x4  __attribute__((ext_vector_type(4)));
typedef int   int2v  __attribute__((ext_vector_type(2)));

__device__ __forceinline__ short f2bf(float f) {
  unsigned u = __builtin_bit_cast(unsigned, f);
  u += 0x7fffu + ((u >> 16) & 1u);   // round-to-nearest-even
  return (short)(u >> 16);
}

__device__ __forceinline__ int packbf(float a, float b) {
  unsigned lo = (unsigned short)f2bf(a);
  unsigned hi = (unsigned short)f2bf(b);
  return (int)(lo | (hi << 16));
}

// PV matrix op: D = A*B + C at 16x16x16 bf16 (A/B = 4 bf16 per lane).
__device__ __forceinline__ f32x4 mfma16(short4v a, short4v b, f32x4 c) {
#if __has_builtin(__builtin_amdgcn_mfma_f32_16x16x16bf16_1k)
  return __builtin_amdgcn_mfma_f32_16x16x16bf16_1k(a, b, c, 0, 0, 0);
#else
  asm("v_mfma_f32_16x16x16_bf16 %0, %1, %2, %0" : "+v"(c) : "v"(a), "v"(b));
  return c;
#endif
}

// async global->LDS DMA, 16B per lane, LDS dest = wave-uniform base + lane*16
__device__ __forceinline__ void gld_lds16(const void* g, void* l) {
  __builtin_amdgcn_global_load_lds(
      (const __attribute__((address_space(1))) unsigned int*)g,
      (__attribute__((address_space(3))) unsigned int*)l, 16, 0, 0);
}

// Fused preprocessing, one launch:
//   blocks [0,512):    V (B,LKV,DV) fp32 -> Vt (B,DV,LKV) bf16
//   blocks [512,1536): K fp32 -> bf16 flat copy
__global__ __launch_bounds__(256) void pre_kernel(const float* __restrict__ K,
                                                  const float* __restrict__ V,
                                                  short* __restrict__ Kb,
                                                  short* __restrict__ Vt) {
  __shared__ float tile[128][33];
  if (blockIdx.x >= 512) {
    int i = (blockIdx.x - 512) * 256 + threadIdx.x;   // 262144 threads x 8 elems
    size_t off = (size_t)i * 8;
    float4 a = *(const float4*)(K + off);
    float4 c = *(const float4*)(K + off + 4);
    short8 o;
    o[0] = f2bf(a.x); o[1] = f2bf(a.y); o[2] = f2bf(a.z); o[3] = f2bf(a.w);
    o[4] = f2bf(c.x); o[5] = f2bf(c.y); o[6] = f2bf(c.z); o[7] = f2bf(c.w);
    *(short8*)(Kb + off) = o;
    return;
  }
  const int bx  = blockIdx.x;
  const int kv0 = (bx & 15) * 128;
  const int dv0 = ((bx >> 4) & 3) * 32;
  const int b   = bx >> 6;
  const int tid = threadIdx.x;
  const float* src = V + ((size_t)b * LKVN + kv0) * DVN + dv0;
#pragma unroll
  for (int it = 0; it < 4; ++it) {
    int idx = it * 256 + tid;
    int r = idx >> 3, c4 = idx & 7;
    float4 v = *(const float4*)(src + (size_t)r * DVN + c4 * 4);
    tile[r][c4 * 4 + 0] = v.x;
    tile[r][c4 * 4 + 1] = v.y;
    tile[r][c4 * 4 + 2] = v.z;
    tile[r][c4 * 4 + 3] = v.w;
  }
  __syncthreads();
  short* dst = Vt + ((size_t)b * DVN + dv0) * LKVN + kv0;
#pragma unroll
  for (int it = 0; it < 2; ++it) {
    int idx = it * 256 + tid;
    int row = idx >> 4, ch = idx & 15;
    short8 o;
#pragma unroll
    for (int j = 0; j < 8; ++j) o[j] = f2bf(tile[ch * 8 + j][row]);
    *(short8*)(dst + (size_t)row * LKVN + ch * 8) = o;
  }
}

// 8-wave two-sweep attention, async double-buffered K staging (R8 skeleton).
// NEW vs R8: the shfl P-exchange is DELETED. PV uses v_mfma_f32_16x16x16_bf16,
// whose B-frag (k = qd*4+j) is exactly the quad each lane already holds in
// pk[t2] after the S MFMA — no ds_bpermute at all. (R6/R7/R8 all measured
// SQ_LDS_BANK_CONFLICT == 5,308,416 exactly; the only invariant LDS ops were
// the 8 bpermutes/tile/wave at ~10 extra cyc each — this removes the whole
// population and shortens the per-tile chain.) V A-frags likewise use k=qd*4+j
// -> 8 B loads at Vw + qd*4, two per dvg (t2=0,1). PV MFMA count doubles
// (k=16 vs 32) at ~10% matrix util — cheap trade.
// Everything else identical to the verified R8: wave w -> (s=w&3 kv-slice of
// 32, g=w>>2 q-group of 16); swapped MFMA S^T = mfma(K,Q); V direct from L2;
// float4 W stores; QT=32, grid 512; K pre-swizzled DMA (m173 pattern).
__global__ __launch_bounds__(512, 4) void attn_kernel(const float* __restrict__ Q,
                                                      const short* __restrict__ Kb,
                                                      const short* __restrict__ Vt,
                                                      float* __restrict__ W,
                                                      float* __restrict__ O) {
  __shared__ __align__(16) short k_lds[2 * 16384];      // 64 KB double buffer
  __shared__ float red_l[4][QT];
  float (*osum)[QT][OSTR] = (float (*)[QT][OSTR])k_lds; // epilogue alias (33.8KB)

  const int tid  = threadIdx.x;
  const int w    = tid >> 6;
  const int lane = tid & 63;
  const int n    = lane & 15;
  const int qd   = lane >> 4;
  const int s    = w & 3;                    // kv slice (32 cols)
  const int g    = w >> 2;                   // q group (16 rows)
  const int b    = blockIdx.x & 7;           // batch -> XCD
  const int q0   = (blockIdx.x >> 3) * QT;

  const short* Kbase = Kb + (size_t)b * LKVN * DQ;
  const short* Vw = Vt + ((size_t)b * DVN + n) * LKVN + s * 32 + qd * 4;  // k=qd*4+j
  float* Wrow = W + ((size_t)b * LQN + q0 + g * 16 + n) * LKVN + s * 32 + qd * 4;

  // DMA source pointers (pre-swizzled). Even/odd j differ in the XOR key bit 2.
  const int drow = lane >> 4;                // 0..3: row within 4-row chunk
  const short* KdmaE = Kbase + (size_t)(16 * w + drow) * DQ +
                       (((lane & 15) ^ drow) * 8);
  const short* KdmaO = Kbase + (size_t)(16 * w + drow) * DQ +
                       (((lane & 15) ^ (4 + drow)) * 8);
  short* ldsw = k_lds + (w * 4) * 512;       // wave's chunk base (lane off implicit)

#define STAGE(bsel, t)                                                          \
  {                                                                             \
    const short* ge = KdmaE + (size_t)(t) * KTI * DQ;                           \
    const short* go = KdmaO + (size_t)(t) * KTI * DQ;                           \
    short* lb = ldsw + (bsel) * 16384;                                          \
    gld_lds16(ge,           lb);                                                \
    gld_lds16(go + 4 * DQ,  lb + 512);                                          \
    gld_lds16(ge + 8 * DQ,  lb + 1024);                                         \
    gld_lds16(go + 12 * DQ, lb + 1536);                                         \
  }

  // MFMA-read base: row = s*32 + t2*16 + n, col = (ks*32 + qd*8) ^ ((n&7)*8)
  const int krow = (s * 32 + n) * 128;
  const int rswz = (n & 7) << 3;

  // Q B-fragments straight from fp32 (per-block one-shot)
  short8 qf[4];
  {
    const float* Qrow = Q + ((size_t)b * LQN + q0 + g * 16 + n) * DQ + qd * 8;
#pragma unroll
    for (int ks = 0; ks < 4; ++ks) {
      float4 f0 = *(const float4*)(Qrow + ks * 32);
      float4 f1 = *(const float4*)(Qrow + ks * 32 + 4);
      short8 o;
      o[0] = f2bf(f0.x); o[1] = f2bf(f0.y); o[2] = f2bf(f0.z); o[3] = f2bf(f0.w);
      o[4] = f2bf(f1.x); o[5] = f2bf(f1.y); o[6] = f2bf(f1.z); o[7] = f2bf(f1.w);
      qf[ks] = o;
    }
  }

  const float scale = 0.08838834764831845f;  // 1/sqrt(128)
  float l_part = 0.f;

  // ---------------- phase 1: per-q row sums of exp(s) ----------------
  STAGE(0, 0)
  __syncthreads();                           // tile 0 staged
  int cur = 0;
  for (int t = 0; t < NT; ++t) {
    if (t + 1 < NT) STAGE(cur ^ 1, t + 1)    // async DMA, covered by body
    const short* kb = k_lds + cur * 16384;
#pragma unroll
    for (int t2 = 0; t2 < 2; ++t2) {
      f32x4 acc = {0.f, 0.f, 0.f, 0.f};
#pragma unroll
      for (int ks = 0; ks < 4; ++ks) {
        short8 kf = *(const short8*)&kb[krow + t2 * 2048 + ((ks * 32 + qd * 8) ^ rswz)];
        acc = __builtin_amdgcn_mfma_f32_16x16x32_bf16(kf, qf[ks], acc, 0, 0, 0);
      }
#pragma unroll
      for (int r = 0; r < 4; ++r) l_part += __expf(acc[r] * scale);
    }
    __syncthreads();                         // drains my DMAs -> next buf ready
    cur ^= 1;
  }

  // reduce l over qd groups (same q lives in lanes n, n+16, n+32, n+48)
  l_part += __shfl_xor(l_part, 16, 64);
  l_part += __shfl_xor(l_part, 32, 64);
  if (lane < 16) red_l[s][g * 16 + lane] = l_part;
  STAGE(0, 0)                                // restage tile 0 under the reduce
  __syncthreads();
  const float rinv =
      1.0f / (red_l[0][g * 16 + n] + red_l[1][g * 16 + n] +
              red_l[2][g * 16 + n] + red_l[3][g * 16 + n]);

  // ---------------- phase 2: W write + PV (no exchange) ----------------
  f32x4 oacc[8];
#pragma unroll
  for (int dvg = 0; dvg < 8; ++dvg) oacc[dvg] = (f32x4){0.f, 0.f, 0.f, 0.f};

  cur = 0;
  for (int t = 0; t < NT; ++t) {
    if (t + 1 < NT) STAGE(cur ^ 1, t + 1)
    const short* kb = k_lds + cur * 16384;
    f32x4 acc[2];
    __builtin_amdgcn_s_setprio(1);
#pragma unroll
    for (int t2 = 0; t2 < 2; ++t2) {
      acc[t2] = (f32x4){0.f, 0.f, 0.f, 0.f};
#pragma unroll
      for (int ks = 0; ks < 4; ++ks) {
        short8 kf = *(const short8*)&kb[krow + t2 * 2048 + ((ks * 32 + qd * 8) ^ rswz)];
        acc[t2] = __builtin_amdgcn_mfma_f32_16x16x32_bf16(kf, qf[ks], acc[t2], 0, 0, 0);
      }
    }
    __builtin_amdgcn_s_setprio(0);

    // V A-frags (k = qd*4+j), 8 B per load, two per dvg — issued before exp
    short4v vf0[8], vf1[8];
#pragma unroll
    for (int dvg = 0; dvg < 8; ++dvg)
      vf0[dvg] = *(const short4v*)(Vw + (size_t)(dvg * 16) * LKVN + t * KTI);
#pragma unroll
    for (int dvg = 0; dvg < 8; ++dvg)
      vf1[dvg] = *(const short4v*)(Vw + (size_t)(dvg * 16) * LKVN + t * KTI + 16);

    // exp + W store + pack; pk[t2] IS the PV B-frag (k = qd*4+j)
    short4v bfr[2];
#pragma unroll
    for (int t2 = 0; t2 < 2; ++t2) {
      float p0 = __expf(acc[t2][0] * scale) * rinv;
      float p1 = __expf(acc[t2][1] * scale) * rinv;
      float p2 = __expf(acc[t2][2] * scale) * rinv;
      float p3 = __expf(acc[t2][3] * scale) * rinv;
      f32x4 st = {p0, p1, p2, p3};
      *(f32x4*)(Wrow + t * KTI + t2 * 16) = st;
      int2v pk = {packbf(p0, p1), packbf(p2, p3)};
      bfr[t2] = __builtin_bit_cast(short4v, pk);
    }

    __builtin_amdgcn_s_setprio(1);
#pragma unroll
    for (int dvg = 0; dvg < 8; ++dvg)
      oacc[dvg] = mfma16(vf0[dvg], bfr[0], oacc[dvg]);
#pragma unroll
    for (int dvg = 0; dvg < 8; ++dvg)
      oacc[dvg] = mfma16(vf1[dvg], bfr[1], oacc[dvg]);
    __builtin_amdgcn_s_setprio(0);

    __syncthreads();                         // drains my DMAs -> next buf ready
    cur ^= 1;
  }

  // ---------------- cross-slice O reduction (osum aliases k_lds; all k_lds
  // readers are past the final loop barrier, so the alias is safe) ----------
  if (s < 2) {
#pragma unroll
    for (int dvg = 0; dvg < 8; ++dvg)
      *(f32x4*)&osum[s][g * 16 + n][dvg * 16 + qd * 4] = oacc[dvg];
  }
  __syncthreads();
  if (s >= 2) {
#pragma unroll
    for (int dvg = 0; dvg < 8; ++dvg) {
      f32x4* p = (f32x4*)&osum[s - 2][g * 16 + n][dvg * 16 + qd * 4];
      *p = *p + oacc[dvg];
    }
  }
  __syncthreads();

  float* Ob = O + ((size_t)b * LQN + q0) * DVN;
  const int qq = tid >> 4;        // 32 q rows, 16 threads each
  const int c0 = (tid & 15) * 8;  // 8 dv per thread
#pragma unroll
  for (int c = 0; c < 2; ++c) {
    f32x4 s0 = *(const f32x4*)&osum[0][qq][c0 + c * 4];
    f32x4 s1 = *(const f32x4*)&osum[1][qq][c0 + c * 4];
    s0 = s0 + s1;
    *(f32x4*)(Ob + (size_t)qq * DVN + c0 + c * 4) = s0;
  }
}

extern "C" void kernel_launch(void* const* d_in, const int* in_sizes, int n_in,
                              void* d_out, int out_size, void* d_ws, size_t ws_size,
                              hipStream_t stream) {
  const float* Q = (const float*)d_in[0];
  const float* K = (const float*)d_in[1];
  const float* V = (const float*)d_in[2];
  float* W = (float*)d_out;                        // (B, LQ, LKV)
  float* O = W + (size_t)BB * LQN * LKVN;          // (B, LQ, DV)
  short* Kb = (short*)d_ws;                        // 4 MB bf16 (B, LKV, D)
  short* Vt = Kb + (size_t)BB * LKVN * DQ;         // 4 MB bf16 (B, DV, LKV)

  pre_kernel<<<1536, 256, 0, stream>>>(K, V, Kb, Vt);
  attn_kernel<<<512, 512, 0, stream>>>(Q, Kb, Vt, W, O);
}